// Round 11
// baseline (182.214 us; speedup 1.0000x reference)
//
#include <hip/hip_runtime.h>
#include <math.h>
#include <stdint.h>

#define EPS     1e-7f
#define NR      8192
#define DX      256
#define DZ      64
#define KNN     5
#define KEEP    6               // per-split kept candidates (packed u32)
#define NSPLIT  8
#define NPOOL   (NSPLIT * KEEP) // 48
#define NCAND   16              // exact-recompute pool in finalize
#define JS      (NR / NSPLIT)   // 1024
#define JT      64              // j-cols per chunk (4 waves x 16)
#define NCHUNK  (JS / JT)       // 16
#define RBLK    32              // i-rows per block (all 4 waves share them)

typedef _Float16 f16x8 __attribute__((ext_vector_type(8)));
typedef _Float16 f16x4 __attribute__((ext_vector_type(4)));
typedef float    f32x4 __attribute__((ext_vector_type(4)));

__device__ __forceinline__ uint32_t umin_(uint32_t a, uint32_t b) { return a < b ? a : b; }
__device__ __forceinline__ uint32_t umax_(uint32_t a, uint32_t b) { return a < b ? b : a; }

// ------------------------------------------------- X -> f16 + row sq-sums (+ zero out)
__global__ __launch_bounds__(256) void split_k(const float* __restrict__ X,
                                               _Float16* __restrict__ Xh,
                                               float* __restrict__ sqX,
                                               float* __restrict__ out) {
    if (blockIdx.x == 0 && threadIdx.x == 0) out[0] = 0.0f;  // finalize runs later on stream
    const int row  = blockIdx.x * 4 + (threadIdx.x >> 6);
    const int lane = threadIdx.x & 63;
    const float4 v = *(const float4*)&X[(size_t)row * DX + lane * 4];
    float s = v.x * v.x + v.y * v.y + v.z * v.z + v.w * v.w;
    f16x4 h;
    h[0] = (_Float16)v.x; h[1] = (_Float16)v.y;
    h[2] = (_Float16)v.z; h[3] = (_Float16)v.w;
    *(f16x4*)&Xh[(size_t)row * DX + lane * 4] = h;
    #pragma unroll
    for (int o = 32; o > 0; o >>= 1) s += __shfl_down(s, o);
    if (lane == 0) sqX[row] = s;
}

// fold one chunk's 8 candidates (one col/lane x 8 row-slots); DIAG=1 adds the self-check
#define FOLD_BODY(DIAG)                                                              \
    _Pragma("unroll")                                                                \
    for (int g = 0; g < 2; ++g) {                                                    \
        _Pragma("unroll")                                                            \
        for (int r = 0; r < 4; ++r) {                                                \
            const float a = (g == 0) ? acc0[r] : acc1[r];                            \
            const float d2 = fmaf(-2.0f, a, sqi[g][r] + sqj);                        \
            uint32_t cand = (__float_as_uint(d2) & 0xFFFFE000u) | (uint32_t)j;       \
            if (DIAG) {                                                              \
                const int i_ = rowbase + g * 16 + quad * 4 + r;                      \
                cand = (j == i_) ? 0xFFFFFFFFu : cand;                               \
            }                                                                        \
            const int q = g * 4 + r;                                                 \
            uint32_t ck = cand;                                                      \
            _Pragma("unroll")                                                        \
            for (int k = 0; k < KNN; ++k) {                                          \
                const uint32_t bk = best[q][k];                                      \
                best[q][k] = umin_(ck, bk); ck = umax_(ck, bk);                      \
            }                                                                        \
        }                                                                            \
    }

// ------------------------------------------------- f16 MFMA GEMM + fused packed top-5
// BARRIER-FREE K-LOOP (R10) + PHASE-STAGGERED CHUNK ORDER (R11): each wave stages its own
// 16-col quarter into a private double-buffered LDS region (no __syncthreads in the loop),
// and every wave visits the 16 chunks in a different rotation. Without the stagger, all
// ~8 resident waves/CU run the DMA/ds_read/VALU phases in lockstep and the pipes serialize
// chip-wide (R6/R8/R10 all plateau ~95-100 us = pipe-sum, not pipe-max). Chunk order is
// irrelevant to correctness: the packed top-k fold is a pure selection.
// CORRECTNESS/PERF NOTES (hard-won):
//  * __launch_bounds__(256,2): min-waves 4 clamps VGPR to 64 -> scratch spill (R4).
//  * NO runtime subscripts into register arrays (R5: 711 MB scratch). Constant-index
//    select chains only.
//  * LDS+barrier staging plateaus ~95 us (R6/R8); barriered dbuf regresses (R7); direct-
//    from-global B regresses hard (R9: scatter, no latency cover).
__global__ __launch_bounds__(256, 2) void mfma_topk_k(const _Float16* __restrict__ Xh,
                                                      const float* __restrict__ sqX,
                                                      uint32_t* __restrict__ partials) {
    __shared__ __align__(16) uint8_t smem[65536];      // 2 bufs x 4 waves x 8 KB
    __shared__ uint32_t mb2[RBLK][4][KNN];             // cross-wave merge (2.5 KB)

    const int tid  = threadIdx.x;
    const int w    = tid >> 6;
    const int lane = tid & 63;
    const int n    = lane & 15;
    const int quad = lane >> 4;
    const int x7   = n & 7;
    const int s    = blockIdx.x & 7;                   // split (XCD-friendly round-robin)
    const int it   = blockIdx.x >> 3;
    const int rowbase = it * RBLK;
    const int jb0  = s * JS;
    // stagger: co-resident blocks (idx differing by ~256) and the 4 waves of a block all
    // start their chunk rotation at different points
    const int phase = ((((unsigned)blockIdx.x >> 8) * 5) ^ (w * 4)) & (NCHUNK - 1);

    // A fragments: 2 rowgroups x 8 k-steps (A layout: row=lane&15, k=quad*8+j)
    f16x8 Ah[2][8];
    #pragma unroll
    for (int g = 0; g < 2; ++g)
        #pragma unroll
        for (int ks = 0; ks < 8; ++ks)
            Ah[g][ks] = *(const f16x8*)(Xh + (size_t)(rowbase + g * 16 + n) * DX
                                        + ks * 32 + quad * 8);

    float sqi[2][4];
    #pragma unroll
    for (int g = 0; g < 2; ++g) {
        const float4 t = *(const float4*)&sqX[rowbase + g * 16 + quad * 4];
        sqi[g][0] = t.x; sqi[g][1] = t.y; sqi[g][2] = t.z; sqi[g][3] = t.w;
    }

    uint32_t best[8][KNN];   // q = g*4+r; ascending; compile-time indices only
    #pragma unroll
    for (int q = 0; q < 8; ++q)
        #pragma unroll
        for (int k = 0; k < KNN; ++k) best[q][k] = 0xFFFFFFFFu;

    // DMA source offsets (elements, relative to Xh + jb*DX): instr u covers private slots
    // q=u*64+lane; row rr=q>>5 (0..15 within wave's 16 cols), chunk16 c16=(q&31)^(rr&7)
    int srcoff[8];
    #pragma unroll
    for (int u = 0; u < 8; ++u) {
        const int rr  = u * 2 + (lane >> 5);
        const int c16 = (lane & 31) ^ (rr & 7);
        srcoff[u] = (w * 16 + rr) * DX + c16 * 8;
    }
    uint8_t* const myreg = smem + w * 8192;            // wave-private region (buf 0)

    // prologue: stage chunk 'phase' into buf 0
    #pragma unroll
    for (int u = 0; u < 8; ++u)
        __builtin_amdgcn_global_load_lds(
            (const __attribute__((address_space(1))) uint32_t*)
                (Xh + (size_t)(jb0 + phase * JT) * DX + srcoff[u]),
            (__attribute__((address_space(3))) uint32_t*)(myreg + u * 1024),
            16, 0, 0);

    for (int t = 0; t < NCHUNK; ++t) {
        const int jc  = (t + phase) & (NCHUNK - 1);    // this wave's chunk this iteration
        const int jcb = jb0 + jc * JT + w * 16;        // wave's col base this chunk
        const int j   = jcb + n;                       // this lane's column
        const float sqj = sqX[j];
        const f16x8* Bbuf = (const f16x8*)smem + (t & 1) * 2048 + w * 512;

        f32x4 acc0, acc1;
        #pragma unroll
        for (int r = 0; r < 4; ++r) { acc0[r] = 0.0f; acc1[r] = 0.0f; }

        #pragma unroll
        for (int ks = 0; ks < 8; ++ks) {
            const f16x8 b = Bbuf[n * 32 + ((ks * 4 + quad) ^ x7)];
            acc0 = __builtin_amdgcn_mfma_f32_16x16x32_f16(Ah[0][ks], b, acc0, 0, 0, 0);
            acc1 = __builtin_amdgcn_mfma_f32_16x16x32_f16(Ah[1][ks], b, acc1, 0, 0, 0);
        }

        // prefetch next chunk into the other private buffer (after this chunk's reads)
        if (t + 1 < NCHUNK) {
            const int jcn = (t + 1 + phase) & (NCHUNK - 1);
            const _Float16* srcb = Xh + (size_t)(jb0 + jcn * JT) * DX;
            uint8_t* db = smem + ((t + 1) & 1) * 32768 + w * 8192;
            #pragma unroll
            for (int u = 0; u < 8; ++u)
                __builtin_amdgcn_global_load_lds(
                    (const __attribute__((address_space(1))) uint32_t*)(srcb + srcoff[u]),
                    (__attribute__((address_space(3))) uint32_t*)(db + u * 1024),
                    16, 0, 0);
        }

        // fold: wave-uniform diagonal test keeps the self-check out of the common path
        if ((jcb < rowbase + RBLK) && (rowbase < jcb + 16)) {
            FOLD_BODY(1)
        } else {
            FOLD_BODY(0)
        }
    }

    // per-q: butterfly-merge sorted-5 across the 16 n-lanes, then LDS dump
    #pragma unroll
    for (int q = 0; q < 8; ++q) {
        uint32_t a0 = best[q][0], a1 = best[q][1], a2 = best[q][2],
                 a3 = best[q][3], a4 = best[q][4];
        #pragma unroll
        for (int mask = 1; mask <= 8; mask <<= 1) {
            const uint32_t b0 = __shfl_xor(a0, mask);
            const uint32_t b1 = __shfl_xor(a1, mask);
            const uint32_t b2 = __shfl_xor(a2, mask);
            const uint32_t b3 = __shfl_xor(a3, mask);
            const uint32_t b4 = __shfl_xor(a4, mask);
            const uint32_t c0 = umin_(a0, b0);
            const uint32_t c1 = umin_(umin_(a1, b1), umax_(a0, b0));
            const uint32_t c2 = umin_(umin_(a2, b2), umin_(umax_(a0, b1), umax_(a1, b0)));
            const uint32_t c3 = umin_(umin_(a3, b3),
                                      umin_(umax_(a1, b1), umin_(umax_(a0, b2), umax_(a2, b0))));
            const uint32_t c4 = umin_(umin_(a4, b4),
                                      umin_(umin_(umax_(a0, b3), umax_(a1, b2)),
                                            umin_(umax_(a2, b1), umax_(a3, b0))));
            a0 = c0; a1 = c1; a2 = c2; a3 = c3; a4 = c4;
        }
        const int rloc = (q >> 2) * 16 + quad * 4 + (q & 3);  // row within the 32
        uint32_t v = a0;                 // lane n emits element n via constant select chain
        v = (n == 1) ? a1 : v;
        v = (n == 2) ? a2 : v;
        v = (n == 3) ? a3 : v;
        v = (n == 4) ? a4 : v;
        if (n < KNN) mb2[rloc][w][n] = v;
    }
    __syncthreads();    // the only block barrier (also drains last chunk's lgkm/vm state)

    // merge 4 sorted-5 lists -> top-6; emit KEEP=6 per row per split
    if (tid < RBLK) {
        const uint32_t a0 = mb2[tid][0][0], a1 = mb2[tid][0][1], a2 = mb2[tid][0][2],
                       a3 = mb2[tid][0][3], a4 = mb2[tid][0][4];
        const uint32_t b0 = mb2[tid][1][0], b1 = mb2[tid][1][1], b2 = mb2[tid][1][2],
                       b3 = mb2[tid][1][3], b4 = mb2[tid][1][4];
        const uint32_t g0 = mb2[tid][2][0], g1 = mb2[tid][2][1], g2 = mb2[tid][2][2],
                       g3 = mb2[tid][2][3], g4 = mb2[tid][2][4];
        const uint32_t h0 = mb2[tid][3][0], h1 = mb2[tid][3][1], h2 = mb2[tid][3][2],
                       h3 = mb2[tid][3][3], h4 = mb2[tid][3][4];
        // e = merge(a,b) first 6; f = merge(g,h) first 6
        const uint32_t e0 = umin_(a0, b0);
        const uint32_t e1 = umin_(umin_(a1, b1), umax_(a0, b0));
        const uint32_t e2 = umin_(umin_(a2, b2), umin_(umax_(a0, b1), umax_(a1, b0)));
        const uint32_t e3 = umin_(umin_(a3, b3), umin_(umax_(a1, b1),
                                 umin_(umax_(a0, b2), umax_(a2, b0))));
        const uint32_t e4 = umin_(umin_(a4, b4), umin_(umin_(umax_(a0, b3), umax_(a1, b2)),
                                 umin_(umax_(a2, b1), umax_(a3, b0))));
        const uint32_t e5 = umin_(umin_(umax_(a0, b4), umax_(a4, b0)),
                                 umin_(umax_(a1, b3), umin_(umax_(a2, b2), umax_(a3, b1))));
        const uint32_t f0 = umin_(g0, h0);
        const uint32_t f1 = umin_(umin_(g1, h1), umax_(g0, h0));
        const uint32_t f2 = umin_(umin_(g2, h2), umin_(umax_(g0, h1), umax_(g1, h0)));
        const uint32_t f3 = umin_(umin_(g3, h3), umin_(umax_(g1, h1),
                                 umin_(umax_(g0, h2), umax_(g2, h0))));
        const uint32_t f4 = umin_(umin_(g4, h4), umin_(umin_(umax_(g0, h3), umax_(g1, h2)),
                                 umin_(umax_(g2, h1), umax_(g3, h0))));
        const uint32_t f5 = umin_(umin_(umax_(g0, h4), umax_(g4, h0)),
                                 umin_(umax_(g1, h3), umin_(umax_(g2, h2), umax_(g3, h1))));
        // o = merge(e,f) first 6 (6+6 -> 6)
        uint32_t o[KEEP];
        o[0] = umin_(e0, f0);
        o[1] = umin_(umin_(e1, f1), umax_(e0, f0));
        o[2] = umin_(umin_(e2, f2), umin_(umax_(e0, f1), umax_(e1, f0)));
        o[3] = umin_(umin_(e3, f3), umin_(umax_(e1, f1),
                     umin_(umax_(e0, f2), umax_(e2, f0))));
        o[4] = umin_(umin_(e4, f4), umin_(umin_(umax_(e0, f3), umax_(e1, f2)),
                     umin_(umax_(e2, f1), umax_(e3, f0))));
        o[5] = umin_(umin_(e5, f5),
                     umin_(umin_(umax_(e0, f4), umax_(e4, f0)),
                           umin_(umax_(e1, f3), umin_(umax_(e2, f2), umax_(e3, f1)))));
        #pragma unroll
        for (int k = 0; k < KEEP; ++k)
            partials[(size_t)(rowbase + tid) * NPOOL + s * KEEP + k] = o[k];
    }
}

// ------------------------------------------------- one wave per row, ROW-COALESCED re-rank:
// bitonic-64 approx sort of the 48-pool; per candidate, all 64 lanes read its X row
// (coalesced); butterfly-reduced exact fp32 dots; bitonic-16 exact (d2,j) sort; lid; loss.
__global__ __launch_bounds__(256) void finalize_k(const uint32_t* __restrict__ parts,
                                                  const float* __restrict__ X,
                                                  const float* __restrict__ Z,
                                                  const float* __restrict__ sqX,
                                                  float* __restrict__ out) {
    __shared__ float wsum[4];
    const int wv   = threadIdx.x >> 6;
    const int lane = threadIdx.x & 63;
    const int i    = blockIdx.x * 4 + wv;

    // bitonic sort the pool across lanes (keys distinct: disjoint j; inert lanes = FFFF)
    uint32_t v = (lane < NPOOL) ? parts[(size_t)i * NPOOL + lane] : 0xFFFFFFFFu;
    #pragma unroll
    for (int kk = 2; kk <= 64; kk <<= 1) {
        #pragma unroll
        for (int jj = kk >> 1; jj > 0; jj >>= 1) {
            const uint32_t o = __shfl_xor(v, jj);
            const bool keepmin = ((lane & kk) == 0) == ((lane & jj) == 0);
            v = keepmin ? umin_(v, o) : umax_(v, o);
        }
    }
    // lanes 0..15 hold the approx top-16 ascending

    const float4 xi = *(const float4*)(X + (size_t)i * DX + lane * 4);

    float p[16];
    #pragma unroll
    for (int c = 0; c < NCAND; ++c) {
        const int jc = (int)(__shfl(v, c) & 0x1FFFu);
        const float4 xj = *(const float4*)(X + (size_t)jc * DX + lane * 4);
        p[c] = fmaf(xi.x, xj.x, fmaf(xi.y, xj.y, fmaf(xi.z, xj.z, xi.w * xj.w)));
    }
    #pragma unroll
    for (int c = 0; c < NCAND; ++c) {
        p[c] += __shfl_xor(p[c], 1);
        p[c] += __shfl_xor(p[c], 2);
        p[c] += __shfl_xor(p[c], 4);
        p[c] += __shfl_xor(p[c], 8);
    }
    const int cs = lane & 15;
    float dotv = p[0];
    dotv = (cs == 1)  ? p[1]  : dotv;
    dotv = (cs == 2)  ? p[2]  : dotv;
    dotv = (cs == 3)  ? p[3]  : dotv;
    dotv = (cs == 4)  ? p[4]  : dotv;
    dotv = (cs == 5)  ? p[5]  : dotv;
    dotv = (cs == 6)  ? p[6]  : dotv;
    dotv = (cs == 7)  ? p[7]  : dotv;
    dotv = (cs == 8)  ? p[8]  : dotv;
    dotv = (cs == 9)  ? p[9]  : dotv;
    dotv = (cs == 10) ? p[10] : dotv;
    dotv = (cs == 11) ? p[11] : dotv;
    dotv = (cs == 12) ? p[12] : dotv;
    dotv = (cs == 13) ? p[13] : dotv;
    dotv = (cs == 14) ? p[14] : dotv;
    dotv = (cs == 15) ? p[15] : dotv;
    dotv += __shfl_xor(dotv, 16);
    dotv += __shfl_xor(dotv, 32);

    unsigned long long k16 = 0xFFFFFFFFFFFFFFFFull;
    const int jl = (int)(v & 0x1FFFu);
    if (lane < NCAND) {
        const float d2x = (sqX[i] + sqX[jl]) - 2.0f * dotv;
        k16 = ((unsigned long long)__float_as_uint(d2x) << 32) | (unsigned)jl;
    }
    #pragma unroll
    for (int kk = 2; kk <= 16; kk <<= 1) {
        #pragma unroll
        for (int jj = kk >> 1; jj > 0; jj >>= 1) {
            const unsigned long long o = __shfl_xor(k16, jj);
            const bool keepmin = ((lane & kk) == 0) == ((lane & jj) == 0);
            k16 = keepmin ? (k16 < o ? k16 : o) : (k16 < o ? o : k16);
        }
    }

    // lanes 0..4 hold the exact top-5 ascending
    const float d2k = __uint_as_float((uint32_t)(k16 >> 32));
    const int   jk  = (int)(k16 & 0x1FFFull);
    float lkx = 0.0f;
    if (lane < KNN) lkx = log10f(sqrtf(fmaxf(d2k, 0.0f)) + EPS);
    const float l4x = __shfl(lkx, KNN - 1);
    float sx = lkx;
    sx += __shfl_xor(sx, 1);
    sx += __shfl_xor(sx, 2);
    sx += __shfl_xor(sx, 4);

    // z-distances, coalesced: 1 dim/lane; 5 neighbor rows read by the whole wave
    const float zi = Z[(size_t)i * DZ + lane];
    float zsum = 0.0f, l4z = 0.0f;
    #pragma unroll
    for (int k = 0; k < KNN; ++k) {
        const int jz = __shfl(jk, k);
        const float zj = Z[(size_t)jz * DZ + lane];
        const float d = zi - zj;
        float s = d * d;
        s += __shfl_xor(s, 1);
        s += __shfl_xor(s, 2);
        s += __shfl_xor(s, 4);
        s += __shfl_xor(s, 8);
        s += __shfl_xor(s, 16);
        s += __shfl_xor(s, 32);
        const float lk = log10f(sqrtf(fmaxf(s, 0.0f)) + EPS);
        zsum += lk;
        if (k == KNN - 1) l4z = lk;     // compile-time branch (unrolled)
    }

    if (lane == 0) {
        const float lx = -(__shfl(sx, 0) - (float)KNN * l4x);
        const float lz = -(zsum - (float)KNN * l4z);
        const float diff = lx - lz;
        wsum[wv] = diff * diff * (1.0f / ((float)NR * KNN * 10.0f));
    }
    __syncthreads();
    if (threadIdx.x == 0)
        atomicAdd(out, wsum[0] + wsum[1] + wsum[2] + wsum[3]);
}

// ---------------------------------------------------------------- launch
extern "C" void kernel_launch(void* const* d_in, const int* in_sizes, int n_in,
                              void* d_out, int out_size, void* d_ws, size_t ws_size,
                              hipStream_t stream) {
    const float* X = (const float*)d_in[0];
    const float* Z = (const float*)d_in[1];
    float* out = (float*)d_out;

    char* ws = (char*)d_ws;
    float*     sqX      = (float*)ws;                         // 32 KB
    uint32_t*  partials = (uint32_t*)(ws + 32768);            // 8192*48*4 = 1.57 MB
    _Float16*  Xh       = (_Float16*)(ws + 32768 + 2097152);  // 4 MB

    split_k<<<NR / 4, 256, 0, stream>>>(X, Xh, sqX, out);
    mfma_topk_k<<<(NR / RBLK) * NSPLIT, 256, 0, stream>>>(Xh, sqX, partials);
    finalize_k<<<NR / 4, 256, 0, stream>>>(partials, X, Z, sqX, out);
}

// Round 12
// 156.358 us; speedup vs baseline: 1.1654x; 1.1654x over previous
//
#include <hip/hip_runtime.h>
#include <math.h>
#include <stdint.h>

#define EPS     1e-7f
#define NR      8192
#define DX      256             // also bytes per fp8 row
#define DZ      64
#define KNN     5
#define KEEP    6               // per-split kept candidates (packed u32)
#define NSPLIT  8
#define NPOOL   (NSPLIT * KEEP) // 48
#define NCAND   16              // exact-recompute pool in finalize
#define JS      (NR / NSPLIT)   // 1024
#define JT      64              // j-cols staged per chunk
#define NCHUNK  (JS / JT)       // 16
#define RBLK    64              // i-rows per block
#define SC1     0x7F7F7F7F      // E8M0 scales = 1.0 in every byte (opsel-proof)

typedef float f32x4 __attribute__((ext_vector_type(4)));
typedef int   i32x8 __attribute__((ext_vector_type(8)));

__device__ __forceinline__ uint32_t umin_(uint32_t a, uint32_t b) { return a < b ? a : b; }
__device__ __forceinline__ uint32_t umax_(uint32_t a, uint32_t b) { return a < b ? b : a; }

// float -> OCP e4m3fn, round-nearest (ties-away; bias irrelevant at this noise level)
__device__ __forceinline__ uint32_t to_e4m3(float f) {
    const uint32_t u = __float_as_uint(f);
    const uint32_t s = (u >> 24) & 0x80u;
    const int e = (int)((u >> 23) & 0xFFu) - 127;
    if (e < -10) return s;                         // underflow to +/-0
    if (e > 8)   return s | 0x7Eu;                 // clamp to 448 (never for N(0,1))
    const uint32_t mant = (u & 0x7FFFFFu) | 0x800000u;
    const int shift = (e < -6) ? (14 - e) : 20;    // subnormal: extra shift
    uint32_t q = (mant + (1u << (shift - 1))) >> shift;
    int E = (e < -6) ? 0 : (e + 7);
    if (q >= 16) { q >>= 1; E += 1; }              // normal rounding carry
    if (E == 0) return s | q;                      // q==8 encodes E=1,m=0 naturally
    return s | ((uint32_t)E << 3) | (q & 7u);
}

// ------------------------------------------------- X -> fp8 + row sq-sums (+ zero out)
__global__ __launch_bounds__(256) void split_k(const float* __restrict__ X,
                                               uint8_t* __restrict__ Xq,
                                               float* __restrict__ sqX,
                                               float* __restrict__ out) {
    if (blockIdx.x == 0 && threadIdx.x == 0) out[0] = 0.0f;  // finalize runs later on stream
    const int row  = blockIdx.x * 4 + (threadIdx.x >> 6);
    const int lane = threadIdx.x & 63;
    const float4 v = *(const float4*)&X[(size_t)row * DX + lane * 4];
    float s = v.x * v.x + v.y * v.y + v.z * v.z + v.w * v.w;
    const uint32_t b = to_e4m3(v.x) | (to_e4m3(v.y) << 8) |
                       (to_e4m3(v.z) << 16) | (to_e4m3(v.w) << 24);
    ((uint32_t*)Xq)[(size_t)row * (DX / 4) + lane] = b;
    #pragma unroll
    for (int o = 32; o > 0; o >>= 1) s += __shfl_down(s, o);
    if (lane == 0) sqX[row] = s;
}

// ------------------------------------------------- MX-fp8 K=128 MFMA GEMM + packed top-5
// R6's proven 2-barrier K-loop, ported to mfma_scale_f32_16x16x128_f8f6f4 with unit
// scales: staged bytes / LDS reads / DMA all halved vs f16, MFMA instructions /4 at 2x
// rate — attacks every pipe of the 94-100 us plateau (which was a pipe-SUM, not a stall:
// R7 dbuf / R10 barrier-free / R11 stagger all neutral-or-worse).
// A/B k-mapping is self-cancelling (same lane->k permutation on both operands leaves the
// dot invariant); C/D layout is shape-determined: col=lane&15, row=quad*4+reg (verified).
// Scales 0x7F7F7F7F are byte-uniform so scale-opsel argument order is harmless.
// CORRECTNESS/PERF NOTES (hard-won):
//  * __launch_bounds__(256,2): min-waves 4 clamps VGPR to 64 -> scratch spill (R4).
//  * NO runtime subscripts into register arrays (R5: 711 MB scratch). Constant-index
//    select chains only.
//  * Selection is approximate; finalize re-ranks exactly in fp32 (noise sigma ~1.4 vs
//    rank-gap ~20 -> margins >10 sigma).
__global__ __launch_bounds__(256, 2) void mfma_topk_k(const uint8_t* __restrict__ Xq,
                                                      const float* __restrict__ sqX,
                                                      uint32_t* __restrict__ partials) {
    __shared__ __align__(16) uint8_t smem[16384];      // B staging: 1024 slots x 16 B
    __shared__ uint32_t mb2[RBLK][2][KNN];             // cross-wave merge (2.5 KB)
    const uint4* Bv = (const uint4*)smem;

    const int tid  = threadIdx.x;
    const int w    = tid >> 6;
    const int lane = tid & 63;
    const int n    = lane & 15;
    const int quad = lane >> 4;
    const int x7   = n & 7;
    const int h    = w >> 1;
    const int sp   = w & 1;
    const int s    = blockIdx.x & 7;                   // split (XCD round-robin)
    const int ib   = (blockIdx.x >> 3) * RBLK;
    const int jb0  = s * JS;
    const int rowbase = ib + h * 32;

    // A fragments: 2 rowgroups x 2 K-halves of 128 (32 B = i32x8 each; 32 VGPR total)
    i32x8 Aq[2][2];
    #pragma unroll
    for (int g = 0; g < 2; ++g)
        #pragma unroll
        for (int kf = 0; kf < 2; ++kf)
            Aq[g][kf] = *(const i32x8*)(Xq + (size_t)(rowbase + g * 16 + n) * DX
                                        + kf * 128 + quad * 32);

    float sqi[2][4];
    #pragma unroll
    for (int g = 0; g < 2; ++g) {
        const float4 t = *(const float4*)&sqX[rowbase + g * 16 + quad * 4];
        sqi[g][0] = t.x; sqi[g][1] = t.y; sqi[g][2] = t.z; sqi[g][3] = t.w;
    }

    uint32_t best[8][KNN];   // q = g*4+r; ascending; compile-time indices only
    #pragma unroll
    for (int q = 0; q < 8; ++q)
        #pragma unroll
        for (int k = 0; k < KNN; ++k) best[q][k] = 0xFFFFFFFFu;

    // staging map: slot q = w*256 + u*64 + lane holds col sj=q>>4, chunk c=(q&15)^(sj&7)
    int srcoff[4];
    #pragma unroll
    for (int u = 0; u < 4; ++u) {
        const int q  = w * 256 + u * 64 + lane;
        const int sj = q >> 4;
        const int c  = (q & 15) ^ (sj & 7);
        srcoff[u] = sj * DX + c * 16;                  // bytes
    }

    for (int jc = 0; jc < NCHUNK; ++jc) {
        const int jb = jb0 + jc * JT;
        __syncthreads();  // previous chunk's readers done
        #pragma unroll
        for (int u = 0; u < 4; ++u) {
            const uint8_t* src = Xq + (size_t)jb * DX + srcoff[u];
            uint8_t* dst = smem + (size_t)(w * 256 + u * 64) * 16;  // uniform; HW +lane*16
            __builtin_amdgcn_global_load_lds((const __attribute__((address_space(1))) uint32_t*)src,
                                             (__attribute__((address_space(3))) uint32_t*)dst,
                                             16, 0, 0);
        }
        __syncthreads();  // drains vmcnt -> staging visible

        f32x4 acc[2][2];  // [si][g]
        #pragma unroll
        for (int si = 0; si < 2; ++si)
            #pragma unroll
            for (int g = 0; g < 2; ++g)
                #pragma unroll
                for (int r = 0; r < 4; ++r) acc[si][g][r] = 0.0f;

        #pragma unroll
        for (int kf = 0; kf < 2; ++kf) {
            #pragma unroll
            for (int si = 0; si < 2; ++si) {
                const int sj = (sp * 2 + si) * 16 + n;         // col within chunk
                const int cb = kf * 8 + quad * 2;              // 16B-chunk base (even)
                const uint4 p0 = Bv[sj * 16 + (cb ^ x7)];
                const uint4 p1 = Bv[sj * 16 + ((cb + 1) ^ x7)];
                i32x8 b;
                b[0] = p0.x; b[1] = p0.y; b[2] = p0.z; b[3] = p0.w;
                b[4] = p1.x; b[5] = p1.y; b[6] = p1.z; b[7] = p1.w;
                acc[si][0] = __builtin_amdgcn_mfma_scale_f32_16x16x128_f8f6f4(
                                 Aq[0][kf], b, acc[si][0], 0, 0, 0, SC1, 0, SC1);
                acc[si][1] = __builtin_amdgcn_mfma_scale_f32_16x16x128_f8f6f4(
                                 Aq[1][kf], b, acc[si][1], 0, 0, 0, SC1, 0, SC1);
            }
        }

        // fold 16 candidates/lane (C layout: col=n, row=quad*4+reg)
        #pragma unroll
        for (int si = 0; si < 2; ++si) {
            const int j = jb + (sp * 2 + si) * 16 + n;
            const float sqj = sqX[j];
            #pragma unroll
            for (int g = 0; g < 2; ++g) {
                #pragma unroll
                for (int r = 0; r < 4; ++r) {
                    const int i = rowbase + g * 16 + quad * 4 + r;
                    const float d2 = fmaf(-2.0f, acc[si][g][r], sqi[g][r] + sqj);
                    uint32_t cand = (__float_as_uint(d2) & 0xFFFFE000u) | (uint32_t)j;
                    cand = (j == i) ? 0xFFFFFFFFu : cand;   // reference drops the diagonal
                    const int q = g * 4 + r;
                    if (cand < best[q][KNN - 1]) {
                        uint32_t ck = cand;
                        #pragma unroll
                        for (int k = 0; k < KNN; ++k) {
                            const uint32_t bk = best[q][k];
                            best[q][k] = umin_(ck, bk); ck = umax_(ck, bk);
                        }
                    }
                }
            }
        }
    }

    // per-q: butterfly-merge sorted-5 across the 16 n-lanes, then LDS dump
    #pragma unroll
    for (int q = 0; q < 8; ++q) {
        uint32_t a0 = best[q][0], a1 = best[q][1], a2 = best[q][2],
                 a3 = best[q][3], a4 = best[q][4];
        #pragma unroll
        for (int mask = 1; mask <= 8; mask <<= 1) {
            const uint32_t b0 = __shfl_xor(a0, mask);
            const uint32_t b1 = __shfl_xor(a1, mask);
            const uint32_t b2 = __shfl_xor(a2, mask);
            const uint32_t b3 = __shfl_xor(a3, mask);
            const uint32_t b4 = __shfl_xor(a4, mask);
            const uint32_t c0 = umin_(a0, b0);
            const uint32_t c1 = umin_(umin_(a1, b1), umax_(a0, b0));
            const uint32_t c2 = umin_(umin_(a2, b2), umin_(umax_(a0, b1), umax_(a1, b0)));
            const uint32_t c3 = umin_(umin_(a3, b3),
                                      umin_(umax_(a1, b1), umin_(umax_(a0, b2), umax_(a2, b0))));
            const uint32_t c4 = umin_(umin_(a4, b4),
                                      umin_(umin_(umax_(a0, b3), umax_(a1, b2)),
                                            umin_(umax_(a2, b1), umax_(a3, b0))));
            a0 = c0; a1 = c1; a2 = c2; a3 = c3; a4 = c4;
        }
        const int rloc = h * 32 + (q >> 2) * 16 + quad * 4 + (q & 3);
        uint32_t v = a0;                 // lane n emits element n via constant select chain
        v = (n == 1) ? a1 : v;
        v = (n == 2) ? a2 : v;
        v = (n == 3) ? a3 : v;
        v = (n == 4) ? a4 : v;
        if (n < KNN) mb2[rloc][sp][n] = v;
    }
    __syncthreads();

    // cross-wave (sp) merge; emit KEEP=6 per row per split
    if (tid < RBLK) {
        const uint32_t a0 = mb2[tid][0][0], a1 = mb2[tid][0][1], a2 = mb2[tid][0][2],
                       a3 = mb2[tid][0][3], a4 = mb2[tid][0][4];
        const uint32_t b0 = mb2[tid][1][0], b1 = mb2[tid][1][1], b2 = mb2[tid][1][2],
                       b3 = mb2[tid][1][3], b4 = mb2[tid][1][4];
        uint32_t o[KEEP];
        o[0] = umin_(a0, b0);
        o[1] = umin_(umin_(a1, b1), umax_(a0, b0));
        o[2] = umin_(umin_(a2, b2), umin_(umax_(a0, b1), umax_(a1, b0)));
        o[3] = umin_(umin_(a3, b3), umin_(umax_(a1, b1), umin_(umax_(a0, b2), umax_(a2, b0))));
        o[4] = umin_(umin_(a4, b4), umin_(umin_(umax_(a0, b3), umax_(a1, b2)),
                                          umin_(umax_(a2, b1), umax_(a3, b0))));
        o[5] = umin_(umin_(umax_(a0, b4), umax_(a4, b0)),
                     umin_(umax_(a1, b3), umin_(umax_(a2, b2), umax_(a3, b1))));
        #pragma unroll
        for (int k = 0; k < KEEP; ++k)
            partials[(size_t)(ib + tid) * NPOOL + s * KEEP + k] = o[k];
    }
}

// ------------------------------------------------- one wave per row, ROW-COALESCED re-rank:
// bitonic-64 approx sort of the 48-pool; per candidate, all 64 lanes read its X row
// (coalesced); butterfly-reduced exact fp32 dots; bitonic-16 exact (d2,j) sort; lid; loss.
__global__ __launch_bounds__(256) void finalize_k(const uint32_t* __restrict__ parts,
                                                  const float* __restrict__ X,
                                                  const float* __restrict__ Z,
                                                  const float* __restrict__ sqX,
                                                  float* __restrict__ out) {
    __shared__ float wsum[4];
    const int wv   = threadIdx.x >> 6;
    const int lane = threadIdx.x & 63;
    const int i    = blockIdx.x * 4 + wv;

    // bitonic sort the pool across lanes (keys distinct: disjoint j; inert lanes = FFFF)
    uint32_t v = (lane < NPOOL) ? parts[(size_t)i * NPOOL + lane] : 0xFFFFFFFFu;
    #pragma unroll
    for (int kk = 2; kk <= 64; kk <<= 1) {
        #pragma unroll
        for (int jj = kk >> 1; jj > 0; jj >>= 1) {
            const uint32_t o = __shfl_xor(v, jj);
            const bool keepmin = ((lane & kk) == 0) == ((lane & jj) == 0);
            v = keepmin ? umin_(v, o) : umax_(v, o);
        }
    }
    // lanes 0..15 hold the approx top-16 ascending

    const float4 xi = *(const float4*)(X + (size_t)i * DX + lane * 4);

    float p[16];
    #pragma unroll
    for (int c = 0; c < NCAND; ++c) {
        const int jc = (int)(__shfl(v, c) & 0x1FFFu);
        const float4 xj = *(const float4*)(X + (size_t)jc * DX + lane * 4);
        p[c] = fmaf(xi.x, xj.x, fmaf(xi.y, xj.y, fmaf(xi.z, xj.z, xi.w * xj.w)));
    }
    #pragma unroll
    for (int c = 0; c < NCAND; ++c) {
        p[c] += __shfl_xor(p[c], 1);
        p[c] += __shfl_xor(p[c], 2);
        p[c] += __shfl_xor(p[c], 4);
        p[c] += __shfl_xor(p[c], 8);
    }
    const int cs = lane & 15;
    float dotv = p[0];
    dotv = (cs == 1)  ? p[1]  : dotv;
    dotv = (cs == 2)  ? p[2]  : dotv;
    dotv = (cs == 3)  ? p[3]  : dotv;
    dotv = (cs == 4)  ? p[4]  : dotv;
    dotv = (cs == 5)  ? p[5]  : dotv;
    dotv = (cs == 6)  ? p[6]  : dotv;
    dotv = (cs == 7)  ? p[7]  : dotv;
    dotv = (cs == 8)  ? p[8]  : dotv;
    dotv = (cs == 9)  ? p[9]  : dotv;
    dotv = (cs == 10) ? p[10] : dotv;
    dotv = (cs == 11) ? p[11] : dotv;
    dotv = (cs == 12) ? p[12] : dotv;
    dotv = (cs == 13) ? p[13] : dotv;
    dotv = (cs == 14) ? p[14] : dotv;
    dotv = (cs == 15) ? p[15] : dotv;
    dotv += __shfl_xor(dotv, 16);
    dotv += __shfl_xor(dotv, 32);

    unsigned long long k16 = 0xFFFFFFFFFFFFFFFFull;
    const int jl = (int)(v & 0x1FFFu);
    if (lane < NCAND) {
        const float d2x = (sqX[i] + sqX[jl]) - 2.0f * dotv;
        k16 = ((unsigned long long)__float_as_uint(d2x) << 32) | (unsigned)jl;
    }
    #pragma unroll
    for (int kk = 2; kk <= 16; kk <<= 1) {
        #pragma unroll
        for (int jj = kk >> 1; jj > 0; jj >>= 1) {
            const unsigned long long o = __shfl_xor(k16, jj);
            const bool keepmin = ((lane & kk) == 0) == ((lane & jj) == 0);
            k16 = keepmin ? (k16 < o ? k16 : o) : (k16 < o ? o : k16);
        }
    }

    // lanes 0..4 hold the exact top-5 ascending
    const float d2k = __uint_as_float((uint32_t)(k16 >> 32));
    const int   jk  = (int)(k16 & 0x1FFFull);
    float lkx = 0.0f;
    if (lane < KNN) lkx = log10f(sqrtf(fmaxf(d2k, 0.0f)) + EPS);
    const float l4x = __shfl(lkx, KNN - 1);
    float sx = lkx;
    sx += __shfl_xor(sx, 1);
    sx += __shfl_xor(sx, 2);
    sx += __shfl_xor(sx, 4);

    // z-distances, coalesced: 1 dim/lane; 5 neighbor rows read by the whole wave
    const float zi = Z[(size_t)i * DZ + lane];
    float zsum = 0.0f, l4z = 0.0f;
    #pragma unroll
    for (int k = 0; k < KNN; ++k) {
        const int jz = __shfl(jk, k);
        const float zj = Z[(size_t)jz * DZ + lane];
        const float d = zi - zj;
        float s = d * d;
        s += __shfl_xor(s, 1);
        s += __shfl_xor(s, 2);
        s += __shfl_xor(s, 4);
        s += __shfl_xor(s, 8);
        s += __shfl_xor(s, 16);
        s += __shfl_xor(s, 32);
        const float lk = log10f(sqrtf(fmaxf(s, 0.0f)) + EPS);
        zsum += lk;
        if (k == KNN - 1) l4z = lk;     // compile-time branch (unrolled)
    }

    if (lane == 0) {
        const float lx = -(__shfl(sx, 0) - (float)KNN * l4x);
        const float lz = -(zsum - (float)KNN * l4z);
        const float diff = lx - lz;
        wsum[wv] = diff * diff * (1.0f / ((float)NR * KNN * 10.0f));
    }
    __syncthreads();
    if (threadIdx.x == 0)
        atomicAdd(out, wsum[0] + wsum[1] + wsum[2] + wsum[3]);
}

// ---------------------------------------------------------------- launch
extern "C" void kernel_launch(void* const* d_in, const int* in_sizes, int n_in,
                              void* d_out, int out_size, void* d_ws, size_t ws_size,
                              hipStream_t stream) {
    const float* X = (const float*)d_in[0];
    const float* Z = (const float*)d_in[1];
    float* out = (float*)d_out;

    char* ws = (char*)d_ws;
    float*     sqX      = (float*)ws;                         // 32 KB
    uint32_t*  partials = (uint32_t*)(ws + 32768);            // 8192*48*4 = 1.57 MB
    uint8_t*   Xq       = (uint8_t*)(ws + 32768 + 2097152);   // 2 MB fp8

    split_k<<<NR / 4, 256, 0, stream>>>(X, Xq, sqX, out);
    mfma_topk_k<<<(NR / RBLK) * NSPLIT, 256, 0, stream>>>(Xq, sqX, partials);
    finalize_k<<<NR / 4, 256, 0, stream>>>(partials, X, Z, sqX, out);
}